// Round 6
// baseline (12922.429 us; speedup 1.0000x reference)
//
#include <hip/hip_runtime.h>
#include <stdint.h>
#include <stddef.h>

// Persistent 2-layer LSTM decoder, B=1024, H=256, T=512.
// R6: 16 groups x 64 chains x 8 WGs x 512 thr (128 blocks). Wave = (gate,
// unit-half) N-split: no weight duplication (~136 VGPR/wave of B-frags),
// 2 waves/SIMD, barrier fan-in 8, co-resident waves are same-group (R5's
// regression was cross-group SIMD interference at 2 blocks/CU).
// Data path (R4-proven): h in XCD-L2 via plain write-through stores + plain
// loads; barrier = wg-scope RMW at L2 + L1-only invalidate; robust XCD
// grouping with wbl2/inv-sc1 fallback for groups that span XCDs (R5-proven).
//
// h-buffer layout (per group, layer, parity): chunked f16
//   idx16 = c*64 + m  (chunk c = k/8 in 0..31, row m in 0..63)
// so an MFMA A-fragment (8 consecutive k for one m) is one 16B chunk.

#define NBLK   128
#define NGROUP 16
#define GWG    8
#define NTHR   512
#define TSTEPS 512
#define MROWS  64

typedef _Float16 half8 __attribute__((ext_vector_type(8)));
typedef float    f32x4 __attribute__((ext_vector_type(4)));

#define OUT_ELEMS   33554432   // 1024*512*64
#define HF_ELEMS    524288     // 2*1024*256
#define HBUF_ELEMS  16384      // 64*256 (f16) per layer/parity
#define GROUP_WS_BYTES 131072  // 4 bufs * 16384 * 2B
#define WS_HBUF_OFF 4096
#define WS_NEEDED   (WS_HBUF_OFF + NGROUP * GROUP_WS_BYTES)  // 2101248 (fits: R4 ran)

// ws control: [0,2048) 16 group ctrs (128B stride); [2048) g1; [2112) g2;
// [2176,2304) xccArr (128 blocks).

#define EXS 1152   // 64*18 floats per exch slot

__device__ __forceinline__ float sigm(float x)   { return 1.0f / (1.0f + __expf(-x)); }
__device__ __forceinline__ float tanh_f(float x) { return 1.0f - 2.0f / (__expf(2.0f * x) + 1.0f); }

// Group barrier. Local (all 8 WGs on one XCD): wg-scope RMW at the XCD L2 +
// L1-only invalidate. Non-local fallback: wbl2 sc1 + device RMW + inv sc1.
// zz = asm-opaque zero (defeats InstCombine's atomicrmw-add-0 -> load fold,
// which would spin on a stale L1 line).
__device__ __forceinline__ void group_barrier(int* ctr, int* phase, int zz, int isLocal) {
  __syncthreads();
  if (threadIdx.x == 0) {
    const int target = GWG * (++(*phase));
    if (isLocal) {
      __hip_atomic_fetch_add(ctr, 1, __ATOMIC_RELEASE, __HIP_MEMORY_SCOPE_WORKGROUP);
      while (__hip_atomic_fetch_add(ctr, zz, __ATOMIC_RELAXED, __HIP_MEMORY_SCOPE_WORKGROUP) < target)
        __builtin_amdgcn_s_sleep(1);
      asm volatile("buffer_inv sc0" ::: "memory");
    } else {
      asm volatile("buffer_wbl2 sc1\n\ts_waitcnt vmcnt(0)" ::: "memory");
      atomicAdd(ctr, 1);
      while (__hip_atomic_load(ctr, __ATOMIC_RELAXED, __HIP_MEMORY_SCOPE_AGENT) < target)
        __builtin_amdgcn_s_sleep(1);
      asm volatile("buffer_inv sc1" ::: "memory");
    }
  }
  __syncthreads();
}

__device__ __forceinline__ half8 ld_frag(const _Float16* buf, int idx16) {
  return *(const half8*)(buf + (size_t)idx16 * 8);
}

// Packed f16x2 store of (col-pair) for row mh into chunk c. Even-u lanes only.
__device__ __forceinline__ void store_h_pair(_Float16* hw, int c, int u, int mh,
                                             float lo, float hi) {
  union { _Float16 h[2]; uint32_t u32; } pk;
  pk.h[0] = (_Float16)lo; pk.h[1] = (_Float16)hi;
  *((uint32_t*)hw + (size_t)(c * MROWS + mh) * 4 + ((u & 7) >> 1)) = pk.u32;
}

__global__ __launch_bounds__(NTHR, 2)
void decoder_kernel(const float* __restrict__ h0in, const float* __restrict__ c0in,
                    const float* __restrict__ Wih0, const float* __restrict__ Whh0,
                    const float* __restrict__ bih0, const float* __restrict__ bhh0,
                    const float* __restrict__ Wih1, const float* __restrict__ Whh1,
                    const float* __restrict__ bih1, const float* __restrict__ bhh1,
                    const float* __restrict__ Wfc,  const float* __restrict__ bfc,
                    float* __restrict__ out, char* __restrict__ ws)
{
  const int tid  = threadIdx.x;
  const int lane = tid & 63;
  const int wv   = tid >> 6;    // 0..7: gate = wv>>1 (i,f,g,o), half = wv&1
  const int gate = wv >> 1;
  const int half = wv & 1;
  const int q    = lane >> 4;   // quad
  const int u    = lane & 15;   // col within 16-unit tile / frag m

  int zz;
  asm volatile("s_mov_b32 %0, 0" : "=s"(zz));

  // ---- robust (xcc-aware) group assignment ----
  __shared__ int s_asn[4];
  __shared__ uint8_t s_x[NBLK];
  {
    uint8_t* xccArr = (uint8_t*)(ws + 2176);
    int* g1 = (int*)(ws + 2048);
    int* g2 = (int*)(ws + 2112);
    if (tid == 0) {
      uint32_t xcc;
      asm volatile("s_getreg_b32 %0, hwreg(HW_REG_XCC_ID)" : "=s"(xcc));
      xcc &= 7;
      __hip_atomic_store(xccArr + blockIdx.x, (uint8_t)xcc,
                         __ATOMIC_RELAXED, __HIP_MEMORY_SCOPE_AGENT);
      atomicAdd(g1, 1);
      while (__hip_atomic_load(g1, __ATOMIC_RELAXED, __HIP_MEMORY_SCOPE_AGENT) < NBLK)
        __builtin_amdgcn_s_sleep(1);
      s_asn[3] = (int)xcc;
    }
    __syncthreads();
    if (tid < NBLK)
      s_x[tid] = __hip_atomic_load(xccArr + tid, __ATOMIC_RELAXED, __HIP_MEMORY_SCOPE_AGENT);
    __syncthreads();
    if (tid == 0) {
      const int xcc = s_asn[3];
      int cnt[8] = {0, 0, 0, 0, 0, 0, 0, 0};
      int rank = 0;
      for (int i = 0; i < NBLK; ++i) {
        const int x = s_x[i];
        cnt[x]++;
        if (x == xcc && i < (int)blockIdx.x) rank++;
      }
      int prefix = 0;
      for (int x = 0; x < xcc; ++x) prefix += cnt[x];
      const int pos = prefix + rank;           // sort by (xcc, blockIdx)
      const int gg = pos >> 3;                 // 8 WGs per group
      const int local = (gg * 8 >= prefix) && (gg * 8 + 8 <= prefix + cnt[xcc]);
      s_asn[0] = gg; s_asn[1] = pos & 7; s_asn[2] = local;
      atomicAdd(g2, 1);
      while (__hip_atomic_load(g2, __ATOMIC_RELAXED, __HIP_MEMORY_SCOPE_AGENT) < NBLK)
        __builtin_amdgcn_s_sleep(1);
    }
    __syncthreads();
  }
  const int g = s_asn[0];        // group 0..15 (64 chains each)
  const int w = s_asn[1];        // member 0..7 (32-unit slice)
  const int isLocal = s_asn[2];

  int* ctr = (int*)(ws + (size_t)g * 128);
  _Float16* hb_base = (_Float16*)(ws + WS_HBUF_OFF + (size_t)g * GROUP_WS_BYTES);
  auto hbL = [&](int layer, int par) { return hb_base + (size_t)(layer * 2 + par) * HBUF_ELEMS; };

  __shared__ __align__(16) _Float16 xbuf[64 * 72];   // 72-elem stride (bank pad)
  __shared__ __align__(16) float    exch[6 * EXS];   // slots wv=0..5, [m*18+u]
  __shared__ __align__(16) float    predbuf[64 * 68];

  // ---------------- weight fragments (register-resident, f16) ----------------
  // gates = act @ W^T; B-frag: n = u (row within this wave's 16-row tile),
  // k = q*8+j. Wave (gate, half) owns rows gate*256 + w*32 + half*16 + u.
  half8 bL0[10]; half8 bL1[16]; half8 bFC[8];
  float biasL0, biasL1, biasFC = 0.0f;
  {
    const int row = gate * 256 + w * 32 + half * 16 + u;
    biasL0 = bih0[row] + bhh0[row];
    biasL1 = bih1[row] + bhh1[row];
    #pragma unroll
    for (int kt = 0; kt < 10; ++kt) {   // L0: K = 64(x) + 256(h0)
      const int k0 = kt * 32 + q * 8;
      const float* src = (kt < 2) ? (Wih0 + (size_t)row * 64 + k0)
                                  : (Whh0 + (size_t)row * 256 + (k0 - 64));
      half8 v;
      #pragma unroll
      for (int j = 0; j < 8; ++j) v[j] = (_Float16)src[j];
      bL0[kt] = v;
    }
    #pragma unroll
    for (int kt = 0; kt < 16; ++kt) {   // L1: K = 256(h0new) + 256(h1)
      const int k0 = kt * 32 + q * 8;
      const float* src = (kt < 8) ? (Wih1 + (size_t)row * 256 + k0)
                                  : (Whh1 + (size_t)row * 256 + (k0 - 256));
      half8 v;
      #pragma unroll
      for (int j = 0; j < 8; ++j) v[j] = (_Float16)src[j];
      bL1[kt] = v;
    }
    if (wv < 4) {                        // FC tile ct = wv (cols wv*16..+15)
      const int rowF = wv * 16 + u;
      biasFC = bfc[rowF];
      #pragma unroll
      for (int kt = 0; kt < 8; ++kt) {
        const float* src = Wfc + (size_t)rowF * 256 + kt * 32 + q * 8;
        half8 v;
        #pragma unroll
        for (int j = 0; j < 8; ++j) v[j] = (_Float16)src[j];
        bFC[kt] = v;
      }
    } else {
      #pragma unroll
      for (int kt = 0; kt < 8; ++kt) bFC[kt] = half8(0);
    }
  }

  // ---------------- state init ----------------
  float c0st[4][4], c1st[4][4];
  #pragma unroll
  for (int mt = 0; mt < 4; ++mt)
    #pragma unroll
    for (int r = 0; r < 4; ++r) { c0st[mt][r] = 0; c1st[mt][r] = 0; }
  if (gate == 3) {  // o-waves own c-state: row m = mt*16+q*4+r, col = w*32+half*16+u
    const int col = w * 32 + half * 16 + u;
    #pragma unroll
    for (int mt = 0; mt < 4; ++mt)
      #pragma unroll
      for (int r = 0; r < 4; ++r) {
        const int ch = g * MROWS + mt * 16 + q * 4 + r;
        c0st[mt][r] = c0in[(size_t)ch * 256 + col];
        c1st[mt][r] = c0in[262144 + (size_t)ch * 256 + col];
      }
  }
  {  // initial h -> parity-1 chunked buffers (WG's 32-unit slice), 8B stores
    const int gi = tid * 4;             // covers 64 rows x 32 cols
    const int e0 = gi & 7;              // 0 or 4
    const int m  = (gi >> 3) & 63;
    const int cc = gi >> 9;             // 0..3
    const int c  = w * 4 + cc;
    const int col = c * 8 + e0;
    #pragma unroll
    for (int l = 0; l < 2; ++l) {
      const float* s = h0in + (size_t)l * 262144 + (size_t)(g * MROWS + m) * 256 + col;
      union { _Float16 h[4]; uint64_t u64; } pk;
      #pragma unroll
      for (int j = 0; j < 4; ++j) pk.h[j] = (_Float16)s[j];
      *((uint64_t*)hbL(l, 1) + ((size_t)(c * MROWS + m) * 2 + (e0 >> 2))) = pk.u64;
    }
  }
  for (int i = tid; i < 64 * 64; i += NTHR) {  // x0: zeros, col 61 = 1 (SOS)
    const int row = i >> 6, col = i & 63;
    xbuf[row * 72 + col] = (col == 61) ? (_Float16)1.0f : (_Float16)0.0f;
  }

  int phase = 0;
  group_barrier(ctr, &phase, zz, isLocal);

  const int cchunk = w * 4 + half * 2 + (u >> 3);  // h-store chunk for this lane

  // ---------------- time loop ----------------
  for (int t = 0; t < TSTEPS; ++t) {
    // ======== Phase A / Layer 0: gates = [x | h0_prev] @ W^T ========
    {
      const _Float16* h0rd = hbL(0, (t + 1) & 1);
      f32x4 acc[4];
      #pragma unroll
      for (int mt = 0; mt < 4; ++mt) {
        f32x4 v; v[0] = biasL0; v[1] = biasL0; v[2] = biasL0; v[3] = biasL0;
        acc[mt] = v;
      }
      #pragma unroll
      for (int kt = 0; kt < 10; ++kt) {
        half8 a[4];
        #pragma unroll
        for (int mt = 0; mt < 4; ++mt) {
          const int m = mt * 16 + u;
          if (kt < 2) a[mt] = *(const half8*)(xbuf + m * 72 + kt * 32 + q * 8);
          else        a[mt] = ld_frag(h0rd, (kt * 4 - 8 + q) * MROWS + m);
        }
        #pragma unroll
        for (int mt = 0; mt < 4; ++mt)
          acc[mt] = __builtin_amdgcn_mfma_f32_16x16x32_f16(a[mt], bL0[kt], acc[mt], 0, 0, 0);
      }
      if (gate < 3) {  // publish activated: sigm(i), sigm(f), tanh(g)
        #pragma unroll
        for (int mt = 0; mt < 4; ++mt)
          #pragma unroll
          for (int r = 0; r < 4; ++r) {
            const int m = mt * 16 + q * 4 + r;
            exch[wv * EXS + m * 18 + u] = (gate == 2) ? tanh_f(acc[mt][r]) : sigm(acc[mt][r]);
          }
      }
      __syncthreads();
      if (gate == 3) {  // cell update
        _Float16* h0wr = hbL(0, t & 1);
        float hv[4][4];
        #pragma unroll
        for (int mt = 0; mt < 4; ++mt)
          #pragma unroll
          for (int r = 0; r < 4; ++r) {
            const int m = mt * 16 + q * 4 + r;
            const float si = exch[(0 + half) * EXS + m * 18 + u];
            const float sf = exch[(2 + half) * EXS + m * 18 + u];
            const float tg = exch[(4 + half) * EXS + m * 18 + u];
            const float cn = sf * c0st[mt][r] + si * tg;
            c0st[mt][r] = cn;
            hv[mt][r] = sigm(acc[mt][r]) * tanh_f(cn);
          }
        #pragma unroll
        for (int mt = 0; mt < 4; ++mt)
          #pragma unroll
          for (int r = 0; r < 4; ++r) {
            const float other = __shfl_xor(hv[mt][r], 1);
            if (!(u & 1))
              store_h_pair(h0wr, cchunk, u, mt * 16 + q * 4 + r, hv[mt][r], other);
          }
      }
    }
    group_barrier(ctr, &phase, zz, isLocal);

    // ======== Phase B / Layer 1: gates = [h0_new | h1_prev] @ W^T ========
    {
      const _Float16* h0nw = hbL(0, t & 1);
      const _Float16* h1rd = hbL(1, (t + 1) & 1);
      f32x4 acc[4];
      #pragma unroll
      for (int mt = 0; mt < 4; ++mt) {
        f32x4 v; v[0] = biasL1; v[1] = biasL1; v[2] = biasL1; v[3] = biasL1;
        acc[mt] = v;
      }
      #pragma unroll
      for (int kt = 0; kt < 16; ++kt) {
        half8 a[4];
        #pragma unroll
        for (int mt = 0; mt < 4; ++mt) {
          const int m = mt * 16 + u;
          if (kt < 8) a[mt] = ld_frag(h0nw, (kt * 4 + q) * MROWS + m);
          else        a[mt] = ld_frag(h1rd, ((kt - 8) * 4 + q) * MROWS + m);
        }
        #pragma unroll
        for (int mt = 0; mt < 4; ++mt)
          acc[mt] = __builtin_amdgcn_mfma_f32_16x16x32_f16(a[mt], bL1[kt], acc[mt], 0, 0, 0);
      }
      if (gate < 3) {
        #pragma unroll
        for (int mt = 0; mt < 4; ++mt)
          #pragma unroll
          for (int r = 0; r < 4; ++r) {
            const int m = mt * 16 + q * 4 + r;
            exch[wv * EXS + m * 18 + u] = (gate == 2) ? tanh_f(acc[mt][r]) : sigm(acc[mt][r]);
          }
      }
      __syncthreads();
      if (gate == 3) {
        _Float16* h1wr = hbL(1, t & 1);
        float hv[4][4];
        #pragma unroll
        for (int mt = 0; mt < 4; ++mt)
          #pragma unroll
          for (int r = 0; r < 4; ++r) {
            const int m = mt * 16 + q * 4 + r;
            const float si = exch[(0 + half) * EXS + m * 18 + u];
            const float sf = exch[(2 + half) * EXS + m * 18 + u];
            const float tg = exch[(4 + half) * EXS + m * 18 + u];
            const float cn = sf * c1st[mt][r] + si * tg;
            c1st[mt][r] = cn;
            hv[mt][r] = sigm(acc[mt][r]) * tanh_f(cn);
          }
        #pragma unroll
        for (int mt = 0; mt < 4; ++mt)
          #pragma unroll
          for (int r = 0; r < 4; ++r) {
            const float other = __shfl_xor(hv[mt][r], 1);
            if (!(u & 1))
              store_h_pair(h1wr, cchunk, u, mt * 16 + q * 4 + r, hv[mt][r], other);
          }
      }
    }
    group_barrier(ctr, &phase, zz, isLocal);

    // ======== Phase C: FC (waves 0..3) + log_softmax + feedback ========
    if (wv < 4) {
      const _Float16* h1nw = hbL(1, t & 1);
      f32x4 acc[4];
      #pragma unroll
      for (int mt = 0; mt < 4; ++mt) {
        f32x4 v; v[0] = biasFC; v[1] = biasFC; v[2] = biasFC; v[3] = biasFC;
        acc[mt] = v;
      }
      #pragma unroll
      for (int kt = 0; kt < 8; ++kt) {
        half8 a[4];
        #pragma unroll
        for (int mt = 0; mt < 4; ++mt)
          a[mt] = ld_frag(h1nw, (kt * 4 + q) * MROWS + mt * 16 + u);
        #pragma unroll
        for (int mt = 0; mt < 4; ++mt)
          acc[mt] = __builtin_amdgcn_mfma_f32_16x16x32_f16(a[mt], bFC[kt], acc[mt], 0, 0, 0);
      }
      #pragma unroll
      for (int mt = 0; mt < 4; ++mt)
        #pragma unroll
        for (int r = 0; r < 4; ++r)
          predbuf[(mt * 16 + q * 4 + r) * 68 + wv * 16 + u] = acc[mt][r];
    }
    __syncthreads();
    if (tid < 256) {
      const int row = tid >> 2;   // group-local chain 0..63
      const int cg  = tid & 3;    // 16-col group
      const float* pr = predbuf + row * 68 + cg * 16;
      float p[16];
      #pragma unroll
      for (int j = 0; j < 16; ++j) p[j] = pr[j];
      float mx = -3.0e38f;
      #pragma unroll
      for (int j = 0; j < 16; ++j)
        if (!(cg == 3 && j == 15)) mx = fmaxf(mx, p[j]);   // exclude col 63 (dur)
      mx = fmaxf(mx, __shfl_xor(mx, 1));
      mx = fmaxf(mx, __shfl_xor(mx, 2));
      float sm = 0.0f;
      #pragma unroll
      for (int j = 0; j < 16; ++j)
        if (!(cg == 3 && j == 15)) sm += __expf(p[j] - mx);
      sm += __shfl_xor(sm, 1);
      sm += __shfl_xor(sm, 2);
      const float lz = mx + __logf(sm);
      const bool ows = ((row >> 3) == w);   // each WG writes 8 of the 64 rows
      float* dst = out + ((size_t)(g * MROWS + row) * TSTEPS + t) * 64 + cg * 16;
      _Float16* xw = xbuf + row * 72 + cg * 16;
      #pragma unroll
      for (int j = 0; j < 16; ++j) {
        const float val = (cg == 3 && j == 15) ? sigm(p[15]) : (p[j] - lz);
        xw[j] = (_Float16)val;                 // feedback x = out (f16)
        if (ows) dst[j] = val;
      }
    }
    __syncthreads();
  }

  // ---------------- final h_f, c_f ----------------
  // h read back from parity-1 buffers (stores guarded by last B2 + buffer_inv);
  // c from o-wave registers.
  if (gate == 3) {
    const _Float16* h0f = hbL(0, 1);
    const _Float16* h1f = hbL(1, 1);
    float* hf = out + OUT_ELEMS;
    float* cf = out + OUT_ELEMS + HF_ELEMS;
    const int col = w * 32 + half * 16 + u;
    const int c8  = col >> 3, e8 = col & 7;
    #pragma unroll
    for (int mt = 0; mt < 4; ++mt)
      #pragma unroll
      for (int r = 0; r < 4; ++r) {
        const int m = mt * 16 + q * 4 + r;
        const int ch = g * MROWS + m;
        const size_t idx = (size_t)ch * 256 + col;
        hf[idx]          = (float)h0f[(size_t)(c8 * MROWS + m) * 8 + e8];
        hf[262144 + idx] = (float)h1f[(size_t)(c8 * MROWS + m) * 8 + e8];
        cf[idx]          = c0st[mt][r];
        cf[262144 + idx] = c1st[mt][r];
      }
  }
}

extern "C" void kernel_launch(void* const* d_in, const int* in_sizes, int n_in,
                              void* d_out, int out_size, void* d_ws, size_t ws_size,
                              hipStream_t stream) {
  (void)in_sizes; (void)n_in; (void)out_size;
  if (ws_size < (size_t)WS_NEEDED) return;

  const float* h0   = (const float*)d_in[1];
  const float* c0   = (const float*)d_in[2];
  const float* Wih0 = (const float*)d_in[3];
  const float* Whh0 = (const float*)d_in[4];
  const float* bih0 = (const float*)d_in[5];
  const float* bhh0 = (const float*)d_in[6];
  const float* Wih1 = (const float*)d_in[7];
  const float* Whh1 = (const float*)d_in[8];
  const float* bih1 = (const float*)d_in[9];
  const float* bhh1 = (const float*)d_in[10];
  const float* Wfc  = (const float*)d_in[11];
  const float* bfc  = (const float*)d_in[12];
  float* outp = (float*)d_out;
  char*  wsp  = (char*)d_ws;

  // zero control region (ctrs, grid counters, xccArr); ws re-poisoned each call
  hipMemsetAsync(d_ws, 0, WS_HBUF_OFF, stream);

  void* args[] = { &h0, &c0, &Wih0, &Whh0, &bih0, &bhh0, &Wih1, &Whh1,
                   &bih1, &bhh1, &Wfc, &bfc, &outp, &wsp };
  hipError_t e = hipLaunchCooperativeKernel((const void*)decoder_kernel,
                                            dim3(NBLK), dim3(NTHR),
                                            args, 0u, stream);
  if (e != hipSuccess) {
    // fallback: plain launch (128 blocks of 8 waves at 2/SIMD are co-resident)
    decoder_kernel<<<dim3(NBLK), dim3(NTHR), 0, stream>>>(
        h0, c0, Wih0, Whh0, bih0, bhh0, Wih1, Whh1, bih1, bhh1, Wfc, bfc, outp, wsp);
  }
}

// Round 7
// 5420.462 us; speedup vs baseline: 2.3840x; 2.3840x over previous
//
#include <hip/hip_runtime.h>
#include <stdint.h>
#include <stddef.h>

// Persistent 2-layer LSTM decoder, B=1024, H=256, T=512.
// R7: 32 groups x 8 WGs x 256 thr = 256 blocks (EXACTLY 1/CU — the only grid
// where balanced XCD dispatch held: R4/R5 ok, R6's 128-block grid broke it ->
// non-local groups -> wbl2-sc1 flush storms, WRITE 530MB, 12.9ms).
// Group owns 32 chains; WG owns 32 units; wave = (unit-half p, role r):
// r=0 holds {i,g} tiles, r=1 holds {f,o} + c-state for the same 16 units ->
// in-lane cell math, one LDS exchange, no weight duplication (240 VGPR/wave).
// Barrier fan-in 8 (was 16), group spans 8 CUs (was 16): less serialization,
// less skew.
// Data path (R4-proven): h in XCD-L2 via plain write-through stores + plain
// loads; barrier = wg-scope RMW at L2 + L1-only invalidate; robust XCD
// grouping with wbl2/inv-sc1 fallback for groups that span XCDs.
//
// h-buffer layout (per group, layer, parity): chunked f16
//   idx16 = c*32 + m  (chunk c = k/8 in 0..31, row m in 0..31)
// so an MFMA A-fragment (8 consecutive k for one m) is one 16B chunk.

#define NBLK   256
#define NGROUP 32
#define GWG    8
#define NTHR   256
#define TSTEPS 512
#define MROWS  32

typedef _Float16 half8 __attribute__((ext_vector_type(8)));
typedef float    f32x4 __attribute__((ext_vector_type(4)));

#define OUT_ELEMS   33554432   // 1024*512*64
#define HF_ELEMS    524288     // 2*1024*256
#define HBUF_ELEMS  8192       // 32*256 (f16) per layer/parity
#define GROUP_WS_BYTES 65536   // 4 bufs * 8192 * 2B
#define WS_HBUF_OFF 4096
#define WS_NEEDED   (WS_HBUF_OFF + NGROUP * GROUP_WS_BYTES)  // 2101248 == R4-proven size

// ws control: [0,2048) 32 group ctrs (64B stride); [2048) g1; [2112) g2;
// [2176,2432) xccArr (256 blocks).

#define EXS 576   // 32*18 floats per exch slot

__device__ __forceinline__ float sigm(float x)   { return 1.0f / (1.0f + __expf(-x)); }
__device__ __forceinline__ float tanh_f(float x) { return 1.0f - 2.0f / (__expf(2.0f * x) + 1.0f); }

// Group barrier. Local (all 8 WGs on one XCD): wg-scope RMW at the XCD L2 +
// L1-only invalidate. Non-local fallback: wbl2 sc1 + device RMW + inv sc1.
// zz = asm-opaque zero (defeats InstCombine's atomicrmw-add-0 -> load fold,
// which would spin on a stale L1 line -> hang, as in R1).
__device__ __forceinline__ void group_barrier(int* ctr, int* phase, int zz, int isLocal) {
  __syncthreads();
  if (threadIdx.x == 0) {
    const int target = GWG * (++(*phase));
    if (isLocal) {
      __hip_atomic_fetch_add(ctr, 1, __ATOMIC_RELEASE, __HIP_MEMORY_SCOPE_WORKGROUP);
      while (__hip_atomic_fetch_add(ctr, zz, __ATOMIC_RELAXED, __HIP_MEMORY_SCOPE_WORKGROUP) < target)
        __builtin_amdgcn_s_sleep(1);
      asm volatile("buffer_inv sc0" ::: "memory");
    } else {
      asm volatile("buffer_wbl2 sc1\n\ts_waitcnt vmcnt(0)" ::: "memory");
      atomicAdd(ctr, 1);
      while (__hip_atomic_load(ctr, __ATOMIC_RELAXED, __HIP_MEMORY_SCOPE_AGENT) < target)
        __builtin_amdgcn_s_sleep(1);
      asm volatile("buffer_inv sc1" ::: "memory");
    }
  }
  __syncthreads();
}

__device__ __forceinline__ half8 ld_frag(const _Float16* buf, int idx16) {
  return *(const half8*)(buf + (size_t)idx16 * 8);
}

// Packed f16x2 store of (col u, col u+1) for row mh into chunk c. Even-u lanes.
__device__ __forceinline__ void store_h_pair(_Float16* hw, int c, int u, int mh,
                                             float lo, float hi) {
  union { _Float16 h[2]; uint32_t u32; } pk;
  pk.h[0] = (_Float16)lo; pk.h[1] = (_Float16)hi;
  *((uint32_t*)hw + (size_t)(c * MROWS + mh) * 4 + ((u & 7) >> 1)) = pk.u32;
}

__global__ __launch_bounds__(NTHR, 1)
void decoder_kernel(const float* __restrict__ h0in, const float* __restrict__ c0in,
                    const float* __restrict__ Wih0, const float* __restrict__ Whh0,
                    const float* __restrict__ bih0, const float* __restrict__ bhh0,
                    const float* __restrict__ Wih1, const float* __restrict__ Whh1,
                    const float* __restrict__ bih1, const float* __restrict__ bhh1,
                    const float* __restrict__ Wfc,  const float* __restrict__ bfc,
                    float* __restrict__ out, char* __restrict__ ws)
{
  const int tid  = threadIdx.x;
  const int lane = tid & 63;
  const int wv   = tid >> 6;    // 0..3
  const int p    = wv >> 1;     // unit half within WG slice
  const int r    = wv & 1;      // role: 0 -> {i,g}, 1 -> {f,o} + cell
  const int q    = lane >> 4;   // quad
  const int u    = lane & 15;   // col within 16-unit tile / frag m

  int zz;
  asm volatile("s_mov_b32 %0, 0" : "=s"(zz));

  // ---- robust (xcc-aware) group assignment ----
  __shared__ int s_asn[4];
  __shared__ uint8_t s_x[NBLK];
  {
    uint8_t* xccArr = (uint8_t*)(ws + 2176);
    int* g1 = (int*)(ws + 2048);
    int* g2 = (int*)(ws + 2112);
    if (tid == 0) {
      uint32_t xcc;
      asm volatile("s_getreg_b32 %0, hwreg(HW_REG_XCC_ID)" : "=s"(xcc));
      xcc &= 7;
      __hip_atomic_store(xccArr + blockIdx.x, (uint8_t)xcc,
                         __ATOMIC_RELAXED, __HIP_MEMORY_SCOPE_AGENT);
      atomicAdd(g1, 1);
      while (__hip_atomic_load(g1, __ATOMIC_RELAXED, __HIP_MEMORY_SCOPE_AGENT) < NBLK)
        __builtin_amdgcn_s_sleep(1);
      s_asn[3] = (int)xcc;
    }
    __syncthreads();
    s_x[tid] = __hip_atomic_load(xccArr + tid, __ATOMIC_RELAXED, __HIP_MEMORY_SCOPE_AGENT);
    __syncthreads();
    if (tid == 0) {
      const int xcc = s_asn[3];
      int cnt[8] = {0, 0, 0, 0, 0, 0, 0, 0};
      int rank = 0;
      for (int i = 0; i < NBLK; ++i) {
        const int x = s_x[i];
        cnt[x]++;
        if (x == xcc && i < (int)blockIdx.x) rank++;
      }
      int prefix = 0;
      for (int x = 0; x < xcc; ++x) prefix += cnt[x];
      const int pos = prefix + rank;           // sort by (xcc, blockIdx)
      const int gg = pos >> 3;                 // 8 WGs per group
      const int local = (gg * 8 >= prefix) && (gg * 8 + 8 <= prefix + cnt[xcc]);
      s_asn[0] = gg; s_asn[1] = pos & 7; s_asn[2] = local;
      atomicAdd(g2, 1);
      while (__hip_atomic_load(g2, __ATOMIC_RELAXED, __HIP_MEMORY_SCOPE_AGENT) < NBLK)
        __builtin_amdgcn_s_sleep(1);
    }
    __syncthreads();
  }
  const int g = s_asn[0];        // group 0..31 (32 chains each)
  const int w = s_asn[1];        // member 0..7 (32-unit slice)
  const int isLocal = s_asn[2];
  const int s = w * 2 + p;       // 16-unit slice index 0..15

  int* ctr = (int*)(ws + (size_t)g * 64);
  _Float16* hb_base = (_Float16*)(ws + WS_HBUF_OFF + (size_t)g * GROUP_WS_BYTES);
  auto hbL = [&](int layer, int par) { return hb_base + (size_t)(layer * 2 + par) * HBUF_ELEMS; };

  __shared__ __align__(16) _Float16 xbuf[MROWS * 72];   // 72-elem stride (bank pad)
  __shared__ __align__(16) float    exch[2 * EXS];      // slot p, [m*18+u]
  __shared__ __align__(16) float    predbuf[MROWS * 68];

  // ---------------- weight fragments (register-resident, f16) ----------------
  // gates = act @ W^T; B-frag: n = u (gate row within 16-row tile), k = q*8+j.
  // r=0 tiles {i(0), g(512)}, r=1 tiles {f(256), o(768)} for units [s*16, s*16+16).
  half8 bL0[2][10]; half8 bL1[2][16]; half8 bFC[8];
  float biasL0[2], biasL1[2], biasFC;
  #pragma unroll
  for (int nt = 0; nt < 2; ++nt) {
    const int base0 = (r == 0) ? (nt == 0 ? 0 : 512) : (nt == 0 ? 256 : 768);
    const int row = base0 + s * 16 + u;
    biasL0[nt] = bih0[row] + bhh0[row];
    biasL1[nt] = bih1[row] + bhh1[row];
    #pragma unroll
    for (int kt = 0; kt < 10; ++kt) {   // L0: K = 64(x) + 256(h0)
      const int k0 = kt * 32 + q * 8;
      const float* src = (kt < 2) ? (Wih0 + (size_t)row * 64 + k0)
                                  : (Whh0 + (size_t)row * 256 + (k0 - 64));
      half8 v;
      #pragma unroll
      for (int j = 0; j < 8; ++j) v[j] = (_Float16)src[j];
      bL0[nt][kt] = v;
    }
    #pragma unroll
    for (int kt = 0; kt < 16; ++kt) {   // L1: K = 256(h0new) + 256(h1)
      const int k0 = kt * 32 + q * 8;
      const float* src = (kt < 8) ? (Wih1 + (size_t)row * 256 + k0)
                                  : (Whh1 + (size_t)row * 256 + (k0 - 256));
      half8 v;
      #pragma unroll
      for (int j = 0; j < 8; ++j) v[j] = (_Float16)src[j];
      bL1[nt][kt] = v;
    }
  }
  {
    const int rowF = wv * 16 + u;   // FC: wave wv owns output cols [wv*16, +16)
    biasFC = bfc[rowF];
    #pragma unroll
    for (int kt = 0; kt < 8; ++kt) {
      const float* src = Wfc + (size_t)rowF * 256 + kt * 32 + q * 8;
      half8 v;
      #pragma unroll
      for (int j = 0; j < 8; ++j) v[j] = (_Float16)src[j];
      bFC[kt] = v;
    }
  }

  // ---------------- state init ----------------
  float c0st[2][4], c1st[2][4], h0sv[2][4], h1sv[2][4];
  #pragma unroll
  for (int mt = 0; mt < 2; ++mt)
    #pragma unroll
    for (int rr = 0; rr < 4; ++rr) { c0st[mt][rr] = 0; c1st[mt][rr] = 0; h0sv[mt][rr] = 0; h1sv[mt][rr] = 0; }
  if (r == 1) {  // role-1 waves own c-state: chain m = mt*16+q*4+rr, col = s*16+u
    const int col = s * 16 + u;
    #pragma unroll
    for (int mt = 0; mt < 2; ++mt)
      #pragma unroll
      for (int rr = 0; rr < 4; ++rr) {
        const int ch = g * MROWS + mt * 16 + q * 4 + rr;
        c0st[mt][rr] = c0in[(size_t)ch * 256 + col];
        c1st[mt][rr] = c0in[262144 + (size_t)ch * 256 + col];
      }
  }
  {  // initial h -> parity-1 chunked buffers (WG's 32-unit slice), 8B stores
    const int gi = tid * 4;             // 32 rows x 32 cols = 1024 f16 per WG
    const int e0 = gi & 7;              // 0 or 4
    const int m  = (gi >> 3) & 31;
    const int cc = gi >> 8;             // 0..3
    const int c  = w * 4 + cc;
    const int col = c * 8 + e0;
    #pragma unroll
    for (int l = 0; l < 2; ++l) {
      const float* src = h0in + (size_t)l * 262144 + (size_t)(g * MROWS + m) * 256 + col;
      union { _Float16 h[4]; uint64_t u64; } pk;
      #pragma unroll
      for (int j = 0; j < 4; ++j) pk.h[j] = (_Float16)src[j];
      *((uint64_t*)hbL(l, 1) + ((size_t)(c * MROWS + m) * 2 + (e0 >> 2))) = pk.u64;
    }
  }
  for (int i = tid; i < MROWS * 64; i += NTHR) {  // x0: zeros, col 61 = 1 (SOS)
    const int row = i >> 6, col = i & 63;
    xbuf[row * 72 + col] = (col == 61) ? (_Float16)1.0f : (_Float16)0.0f;
  }

  int phase = 0;
  group_barrier(ctr, &phase, zz, isLocal);

  const int cchunk = s * 2 + (u >> 3);  // h-store chunk for this lane

  // ---------------- time loop ----------------
  for (int t = 0; t < TSTEPS; ++t) {
    // ======== Layer 0: gates = [x | h0_prev] @ W^T ========
    {
      const _Float16* h0rd = hbL(0, (t + 1) & 1);
      f32x4 acc[2][2];
      #pragma unroll
      for (int mt = 0; mt < 2; ++mt)
        #pragma unroll
        for (int nt = 0; nt < 2; ++nt) {
          f32x4 v; v[0] = biasL0[nt]; v[1] = biasL0[nt]; v[2] = biasL0[nt]; v[3] = biasL0[nt];
          acc[mt][nt] = v;
        }
      #pragma unroll
      for (int kt = 0; kt < 10; ++kt) {
        half8 a[2];
        #pragma unroll
        for (int mt = 0; mt < 2; ++mt) {
          const int m = mt * 16 + u;
          if (kt < 2) a[mt] = *(const half8*)(xbuf + m * 72 + kt * 32 + q * 8);
          else        a[mt] = ld_frag(h0rd, (kt * 4 - 8 + q) * MROWS + m);
        }
        #pragma unroll
        for (int mt = 0; mt < 2; ++mt)
          #pragma unroll
          for (int nt = 0; nt < 2; ++nt)
            acc[mt][nt] = __builtin_amdgcn_mfma_f32_16x16x32_f16(a[mt], bL0[nt][kt], acc[mt][nt], 0, 0, 0);
      }
      if (r == 0) {  // u0 = sigm(i)*tanh(g) in-lane (tile0=i, tile1=g)
        #pragma unroll
        for (int mt = 0; mt < 2; ++mt)
          #pragma unroll
          for (int rr = 0; rr < 4; ++rr)
            exch[p * EXS + (mt * 16 + q * 4 + rr) * 18 + u] =
                sigm(acc[mt][0][rr]) * tanh_f(acc[mt][1][rr]);
      }
      __syncthreads();
      if (r == 1) {  // tile0=f, tile1=o
        _Float16* h0wr = hbL(0, t & 1);
        float hv[2][4];
        #pragma unroll
        for (int mt = 0; mt < 2; ++mt)
          #pragma unroll
          for (int rr = 0; rr < 4; ++rr) {
            const float u0 = exch[p * EXS + (mt * 16 + q * 4 + rr) * 18 + u];
            const float cn = sigm(acc[mt][0][rr]) * c0st[mt][rr] + u0;
            c0st[mt][rr] = cn;
            const float hh = sigm(acc[mt][1][rr]) * tanh_f(cn);
            h0sv[mt][rr] = hh; hv[mt][rr] = hh;
          }
        #pragma unroll
        for (int mt = 0; mt < 2; ++mt)
          #pragma unroll
          for (int rr = 0; rr < 4; ++rr) {
            const float other = __shfl_xor(hv[mt][rr], 1);
            if (!(u & 1))
              store_h_pair(h0wr, cchunk, u, mt * 16 + q * 4 + rr, hv[mt][rr], other);
          }
      }
    }
    group_barrier(ctr, &phase, zz, isLocal);

    // ======== Layer 1: gates = [h0_new | h1_prev] @ W^T ========
    {
      const _Float16* h0nw = hbL(0, t & 1);
      const _Float16* h1rd = hbL(1, (t + 1) & 1);
      f32x4 acc[2][2];
      #pragma unroll
      for (int mt = 0; mt < 2; ++mt)
        #pragma unroll
        for (int nt = 0; nt < 2; ++nt) {
          f32x4 v; v[0] = biasL1[nt]; v[1] = biasL1[nt]; v[2] = biasL1[nt]; v[3] = biasL1[nt];
          acc[mt][nt] = v;
        }
      #pragma unroll
      for (int kt = 0; kt < 16; ++kt) {
        half8 a[2];
        #pragma unroll
        for (int mt = 0; mt < 2; ++mt) {
          const int m = mt * 16 + u;
          if (kt < 8) a[mt] = ld_frag(h0nw, (kt * 4 + q) * MROWS + m);
          else        a[mt] = ld_frag(h1rd, ((kt - 8) * 4 + q) * MROWS + m);
        }
        #pragma unroll
        for (int mt = 0; mt < 2; ++mt)
          #pragma unroll
          for (int nt = 0; nt < 2; ++nt)
            acc[mt][nt] = __builtin_amdgcn_mfma_f32_16x16x32_f16(a[mt], bL1[nt][kt], acc[mt][nt], 0, 0, 0);
      }
      if (r == 0) {
        #pragma unroll
        for (int mt = 0; mt < 2; ++mt)
          #pragma unroll
          for (int rr = 0; rr < 4; ++rr)
            exch[p * EXS + (mt * 16 + q * 4 + rr) * 18 + u] =
                sigm(acc[mt][0][rr]) * tanh_f(acc[mt][1][rr]);
      }
      __syncthreads();
      if (r == 1) {
        _Float16* h1wr = hbL(1, t & 1);
        float hv[2][4];
        #pragma unroll
        for (int mt = 0; mt < 2; ++mt)
          #pragma unroll
          for (int rr = 0; rr < 4; ++rr) {
            const float u0 = exch[p * EXS + (mt * 16 + q * 4 + rr) * 18 + u];
            const float cn = sigm(acc[mt][0][rr]) * c1st[mt][rr] + u0;
            c1st[mt][rr] = cn;
            const float hh = sigm(acc[mt][1][rr]) * tanh_f(cn);
            h1sv[mt][rr] = hh; hv[mt][rr] = hh;
          }
        #pragma unroll
        for (int mt = 0; mt < 2; ++mt)
          #pragma unroll
          for (int rr = 0; rr < 4; ++rr) {
            const float other = __shfl_xor(hv[mt][rr], 1);
            if (!(u & 1))
              store_h_pair(h1wr, cchunk, u, mt * 16 + q * 4 + rr, hv[mt][rr], other);
          }
      }
    }
    group_barrier(ctr, &phase, zz, isLocal);

    // ======== FC + log_softmax (redundant per WG; wave wv = one 16-col tile) ========
    {
      const _Float16* h1nw = hbL(1, t & 1);
      f32x4 acc[2];
      #pragma unroll
      for (int mt = 0; mt < 2; ++mt) {
        f32x4 v; v[0] = biasFC; v[1] = biasFC; v[2] = biasFC; v[3] = biasFC;
        acc[mt] = v;
      }
      #pragma unroll
      for (int kt = 0; kt < 8; ++kt) {
        half8 a[2];
        #pragma unroll
        for (int mt = 0; mt < 2; ++mt)
          a[mt] = ld_frag(h1nw, (kt * 4 + q) * MROWS + mt * 16 + u);
        #pragma unroll
        for (int mt = 0; mt < 2; ++mt)
          acc[mt] = __builtin_amdgcn_mfma_f32_16x16x32_f16(a[mt], bFC[kt], acc[mt], 0, 0, 0);
      }
      #pragma unroll
      for (int mt = 0; mt < 2; ++mt)
        #pragma unroll
        for (int rr = 0; rr < 4; ++rr)
          predbuf[(mt * 16 + q * 4 + rr) * 68 + wv * 16 + u] = acc[mt][rr];
    }
    __syncthreads();
    if (tid < 128) {
      const int row = tid >> 2;   // group-local chain 0..31
      const int cg  = tid & 3;    // 16-col group
      const float* pr = predbuf + row * 68 + cg * 16;
      float pv[16];
      #pragma unroll
      for (int j = 0; j < 16; ++j) pv[j] = pr[j];
      float mx = -3.0e38f;
      #pragma unroll
      for (int j = 0; j < 16; ++j)
        if (!(cg == 3 && j == 15)) mx = fmaxf(mx, pv[j]);   // exclude col 63 (dur)
      mx = fmaxf(mx, __shfl_xor(mx, 1));
      mx = fmaxf(mx, __shfl_xor(mx, 2));
      float sm = 0.0f;
      #pragma unroll
      for (int j = 0; j < 16; ++j)
        if (!(cg == 3 && j == 15)) sm += __expf(pv[j] - mx);
      sm += __shfl_xor(sm, 1);
      sm += __shfl_xor(sm, 2);
      const float lz = mx + __logf(sm);
      const bool ows = ((row >> 2) == w);   // each WG writes 4 of the 32 rows
      float* dst = out + ((size_t)(g * MROWS + row) * TSTEPS + t) * 64 + cg * 16;
      _Float16* xw = xbuf + row * 72 + cg * 16;
      #pragma unroll
      for (int j = 0; j < 16; ++j) {
        const float val = (cg == 3 && j == 15) ? sigm(pv[15]) : (pv[j] - lz);
        xw[j] = (_Float16)val;                 // feedback x = out (f16)
        if (ows) dst[j] = val;
      }
    }
    __syncthreads();
  }

  // ---------------- final h_f, c_f ----------------
  if (r == 1) {
    float* hf = out + OUT_ELEMS;
    float* cf = out + OUT_ELEMS + HF_ELEMS;
    const int col = s * 16 + u;
    #pragma unroll
    for (int mt = 0; mt < 2; ++mt)
      #pragma unroll
      for (int rr = 0; rr < 4; ++rr) {
        const int ch = g * MROWS + mt * 16 + q * 4 + rr;
        const size_t idx = (size_t)ch * 256 + col;
        hf[idx]          = h0sv[mt][rr];
        hf[262144 + idx] = h1sv[mt][rr];
        cf[idx]          = c0st[mt][rr];
        cf[262144 + idx] = c1st[mt][rr];
      }
  }
}

extern "C" void kernel_launch(void* const* d_in, const int* in_sizes, int n_in,
                              void* d_out, int out_size, void* d_ws, size_t ws_size,
                              hipStream_t stream) {
  (void)in_sizes; (void)n_in; (void)out_size;
  if (ws_size < (size_t)WS_NEEDED) return;

  const float* h0   = (const float*)d_in[1];
  const float* c0   = (const float*)d_in[2];
  const float* Wih0 = (const float*)d_in[3];
  const float* Whh0 = (const float*)d_in[4];
  const float* bih0 = (const float*)d_in[5];
  const float* bhh0 = (const float*)d_in[6];
  const float* Wih1 = (const float*)d_in[7];
  const float* Whh1 = (const float*)d_in[8];
  const float* bih1 = (const float*)d_in[9];
  const float* bhh1 = (const float*)d_in[10];
  const float* Wfc  = (const float*)d_in[11];
  const float* bfc  = (const float*)d_in[12];
  float* outp = (float*)d_out;
  char*  wsp  = (char*)d_ws;

  // zero control region (ctrs, grid counters, xccArr); ws re-poisoned each call
  hipMemsetAsync(d_ws, 0, WS_HBUF_OFF, stream);

  void* args[] = { &h0, &c0, &Wih0, &Whh0, &bih0, &bhh0, &Wih1, &Whh1,
                   &bih1, &bhh1, &Wfc, &bfc, &outp, &wsp };
  hipError_t e = hipLaunchCooperativeKernel((const void*)decoder_kernel,
                                            dim3(NBLK), dim3(NTHR),
                                            args, 0u, stream);
  if (e != hipSuccess) {
    // fallback: plain launch (256 blocks, 1/CU, co-resident)
    decoder_kernel<<<dim3(NBLK), dim3(NTHR), 0, stream>>>(
        h0, c0, Wih0, Whh0, bih0, bhh0, Wih1, Whh1, bih1, bhh1, Wfc, bfc, outp, wsp);
  }
}